// Round 9
// baseline (767.938 us; speedup 1.0000x reference)
//
#include <hip/hip_runtime.h>
#include <math.h>

// Problem constants
#define B_   16
#define C_   64
#define OC_  64
#define H_   128
#define W_   128
#define E_   4
#define HID_ 16
#define HW_  (H_ * W_)          // 16384
#define TEMP_ 30.0f

// Activation plane: [kind(h=0,l=1)][chunk(0,1)][b][hw][32ch], bf16.
#define PSTR ((size_t)B_ * HW_ * 32)
// Weight array per layer (merged hi+lo), shorts:
// [b][chunk2][kind2][tap9][s=lq*4+oct (16)][ln16][8ch]
#define WELEM 1179648

typedef float f32x4 __attribute__((ext_vector_type(4)));
typedef short s16x8 __attribute__((ext_vector_type(8)));
typedef short s16x4 __attribute__((ext_vector_type(4)));

__device__ __forceinline__ unsigned short f2bf(float f) {
    unsigned u = __float_as_uint(f);
    u = u + 0x7FFFu + ((u >> 16) & 1u);          // round-to-nearest-even
    return (unsigned short)(u >> 16);
}
__device__ __forceinline__ float bf2f(unsigned short h) {
    return __uint_as_float(((unsigned)h) << 16);
}

// ---------------------------------------------------------------------------
// K1: global average pool. One block per (b,c).
// ---------------------------------------------------------------------------
__global__ void pool_kernel(const float* __restrict__ x, float* __restrict__ pooled) {
    int bc = blockIdx.x;
    const float4* xp = (const float4*)(x + (size_t)bc * HW_);
    float s = 0.f;
    for (int i = threadIdx.x; i < HW_ / 4; i += 256) {
        float4 v = xp[i];
        s += v.x + v.y + v.z + v.w;
    }
    for (int off = 32; off; off >>= 1) s += __shfl_down(s, off, 64);
    __shared__ float red[4];
    int lane = threadIdx.x & 63, wv = threadIdx.x >> 6;
    if (lane == 0) red[wv] = s;
    __syncthreads();
    if (threadIdx.x == 0)
        pooled[bc] = (red[0] + red[1] + red[2] + red[3]) * (1.0f / (float)HW_);
}

// ---------------------------------------------------------------------------
// K2: control MLP + softmax + mixed biases (3 layers). grid=B_, block=64.
// ---------------------------------------------------------------------------
__global__ void control_kernel(const float* __restrict__ pooled,
                               const float* __restrict__ cw1,
                               const float* __restrict__ cw2,
                               const float* __restrict__ b1,
                               const float* __restrict__ b2,
                               const float* __restrict__ b3,
                               float* __restrict__ coeff,
                               float* __restrict__ ab_all) {
    int b = blockIdx.x;
    int t = threadIdx.x;                // oc
    __shared__ float pl[C_];
    __shared__ float hid[HID_];
    pl[t] = pooled[b * C_ + t];
    __syncthreads();
    if (t < HID_) {
        float a = 0.f;
        for (int c = 0; c < C_; ++c) a = fmaf(pl[c], cw1[t * C_ + c], a);
        hid[t] = fmaxf(a, 0.f);
    }
    __syncthreads();
    float l[E_];
#pragma unroll
    for (int e = 0; e < E_; ++e) {
        float a = 0.f;
#pragma unroll
        for (int h = 0; h < HID_; ++h) a = fmaf(hid[h], cw2[(t * E_ + e) * HID_ + h], a);
        l[e] = a * (1.0f / TEMP_);
    }
    float m = fmaxf(fmaxf(l[0], l[1]), fmaxf(l[2], l[3]));
    float p[E_], s = 0.f;
#pragma unroll
    for (int e = 0; e < E_; ++e) { p[e] = expf(l[e] - m); s += p[e]; }
    float inv = 1.0f / s;
#pragma unroll
    for (int e = 0; e < E_; ++e) { p[e] *= inv; coeff[(b * OC_ + t) * E_ + e] = p[e]; }
    float a1 = 0.f, a2 = 0.f, a3 = 0.f;
#pragma unroll
    for (int e = 0; e < E_; ++e) {
        a1 = fmaf(p[e], b1[e * OC_ + t], a1);
        a2 = fmaf(p[e], b2[e * OC_ + t], a2);
        a3 = fmaf(p[e], b3[e * OC_ + t], a3);
    }
    ab_all[0 * B_ * OC_ + b * OC_ + t] = a1;
    ab_all[1 * B_ * OC_ + b * OC_ + t] = a2;
    ab_all[2 * B_ * OC_ + b * OC_ + t] = a3;
}

// ---------------------------------------------------------------------------
// K3: mix expert weights, split to bf16 hi/lo, write COALESCED A-frag layout:
// shorts offset = T*2048 + s*128 + ln*8 + j,
//   T = ((b*2+chunk)*2+kind)*9 + tap,  s = lq*4+oct,  oc = oct*16+ln,
//   c = chunk*32 + lq*8 + j.
// A wave's A-fragment load (fixed oct) = 4x256B contiguous chunks, full lines.
// ---------------------------------------------------------------------------
__global__ void aggw_split(const float* __restrict__ coeff,
                           const float* __restrict__ w1,
                           const float* __restrict__ w2,
                           const float* __restrict__ w3,
                           unsigned short* __restrict__ W1,
                           unsigned short* __restrict__ W2,
                           unsigned short* __restrict__ W3) {
    int layer = blockIdx.y;
    const float* w = (layer == 0) ? w1 : (layer == 1) ? w2 : w3;
    unsigned short* W = (layer == 0) ? W1 : (layer == 1) ? W2 : W3;

    int idx = blockIdx.x * 256 + threadIdx.x;     // < 589824
    int c   = idx & 63;
    int r   = idx >> 6;
    int tap = r % 9;
    int r2  = r / 9;
    int oc  = r2 & 63;
    int b   = r2 >> 6;

    float s = 0.f;
#pragma unroll
    for (int e = 0; e < E_; ++e)
        s = fmaf(coeff[(b * OC_ + oc) * E_ + e],
                 w[(((size_t)e * OC_ + oc) * C_ + c) * 9 + tap], s);
    unsigned short h = f2bf(s);
    unsigned short lo = f2bf(s - bf2f(h));

    int chunk = c >> 5, lq = (c >> 3) & 3, j = c & 7;
    int oct = oc >> 4, ln = oc & 15;
    int sidx = lq * 4 + oct;
    size_t T0 = ((size_t)(b * 2 + chunk) * 2 + 0) * 9 + tap;
    size_t T1 = ((size_t)(b * 2 + chunk) * 2 + 1) * 9 + tap;
    W[T0 * 2048 + sidx * 128 + ln * 8 + j] = h;
    W[T1 * 2048 + sidx * 128 + ln * 8 + j] = lo;
}

// ---------------------------------------------------------------------------
// K4: convert+transpose x: fp32 [b][c][hw] -> 4 bf16 planes [k][chunk][b][hw][32].
// ---------------------------------------------------------------------------
__global__ void xcvt_kernel(const float* __restrict__ x,
                            unsigned short* __restrict__ Xs) {
    __shared__ float tr[64][65];
    const int b   = blockIdx.y;
    const int hw0 = blockIdx.x * 64;
    const int t   = threadIdx.x;
    const int l   = t & 63;
    const int wv  = t >> 6;
    const float* src = x + (size_t)b * C_ * HW_;
#pragma unroll
    for (int i = 0; i < 16; ++i) {
        int c = wv * 16 + i;
        tr[l][c] = src[(size_t)c * HW_ + hw0 + l];
    }
    __syncthreads();
#pragma unroll
    for (int i = 0; i < 2; ++i) {
        int g  = t + i * 256;                 // < 512
        int px = g >> 3;
        int cg = (g & 7) << 3;
        s16x8 hv, lv;
#pragma unroll
        for (int j = 0; j < 8; ++j) {
            float v = tr[px][cg + j];
            unsigned short h = f2bf(v);
            hv[j] = (short)h;
            lv[j] = (short)f2bf(v - bf2f(h));
        }
        int chunk = cg >> 5;
        int off   = cg & 31;
        size_t base = ((size_t)b * HW_ + hw0 + px) * 32 + off;
        *(s16x8*)(Xs + (size_t)(0 + chunk) * PSTR + base) = hv;
        *(s16x8*)(Xs + (size_t)(2 + chunk) * PSTR + base) = lv;
    }
}

// ---------------------------------------------------------------------------
// K5 v6: split-bf16 MFMA conv; coalesced JIT weight loads; R5-style X staging.
// Grid 2048 (XCD-swizzled), 256 thr (4 waves), block = 1 out row x 128 px x 64 oc.
// Wave wv = qx (px quarter, 2 nt of 16); acc[4 oct][2 nt].
// 4 phases = X planes in order (h,c0) (l,c0) (h,c1) (l,c1):
//   h-phase: acc += Wh*Xh + Wl*Xh  (16 MFMA/tap); l-phase: acc += Wh*Xl (8).
// LDS (single buffer, 24,960 B): [3 rows][65 pairs][8 slots][8ch],
//   stage: LINEAR coalesced global reads -> stg regs -> ds_write with slot XOR
//   (slot^(pr&7)); read slot (u*4+lq)^(pr&7) -> exact 8-touch/bank minimum.
// Weights: JIT per-tap loads from the coalesced layout (no ping-pong); latency
//   hidden by 16 waves/CU (4 blocks) TLP.
// ---------------------------------------------------------------------------
__launch_bounds__(256, 4)
__global__ void conv_mfma(const unsigned short* __restrict__ Xs,
                          const unsigned short* __restrict__ W,
                          const float* __restrict__ bias,
                          unsigned short* __restrict__ Ys,
                          float* __restrict__ Yf,
                          int final_layer) {
    const int bid = blockIdx.x;
    const int wg  = (bid & 7) * 256 + (bid >> 3);    // XCD-bijective (2048 = 8*256)
    const int b   = wg >> 7;
    const int py  = wg & 127;

    const int t  = threadIdx.x;
    const int l  = t & 63;
    const int wv = t >> 6;
    const int lq = l >> 4;
    const int ln = l & 15;
    const int qx = wv;               // px quarter (0..3)

    __shared__ __align__(16) unsigned short lds_x[1560 * 8];   // 24,960 B

    f32x4 acc[4][2];
#pragma unroll
    for (int o = 0; o < 4; ++o)
#pragma unroll
        for (int n = 0; n < 2; ++n)
#pragma unroll
            for (int r = 0; r < 4; ++r) acc[o][n][r] = 0.f;

    const size_t pbase = (size_t)b * HW_ * 32;
    s16x8 stg[7];

    // ---- stage plane `pl4` (in [k*2+chunk]) : linear coalesced reads ----
#define ISSUE(pl4)                                                             \
    {                                                                          \
        const unsigned short* p_ = Xs + (size_t)(pl4) * PSTR + pbase;          \
        _Pragma("unroll")                                                      \
        for (int i = 0; i < 7; ++i) {                                          \
            int g = t + i * 256;                                               \
            if (i < 6 || g < 1560) {                                           \
                int row = g / 520;                                             \
                int rem = g - row * 520;                                       \
                int pr  = rem >> 3;                                            \
                int sl  = rem & 7;                                             \
                int u = sl >> 2, q = sl & 3;                                   \
                int ir = py + row - 1;                                         \
                int ic = 2 * pr + u - 1;                                       \
                s16x8 v;                                                       \
                _Pragma("unroll")                                              \
                for (int j = 0; j < 8; ++j) v[j] = 0;                          \
                if ((unsigned)ir < (unsigned)H_ && (unsigned)ic < (unsigned)W_)\
                    v = *(const s16x8*)(p_ + ((size_t)(ir * W_ + ic)) * 32 + q * 8); \
                stg[i] = v;                                                    \
            }                                                                  \
        }                                                                      \
    }

    // ---- ds_write with XOR'd slot (swizzle on LDS side) ----
#define WRITE_STG()                                                            \
    {                                                                          \
        _Pragma("unroll")                                                      \
        for (int i = 0; i < 7; ++i) {                                          \
            int g = t + i * 256;                                               \
            if (i < 6 || g < 1560) {                                           \
                int row = g / 520;                                             \
                int rem = g - row * 520;                                       \
                int pr  = rem >> 3;                                            \
                int sl  = rem & 7;                                             \
                *(s16x8*)&lds_x[(row * 520 + pr * 8 + (sl ^ (pr & 7))) * 8] = stg[i]; \
            }                                                                  \
        }                                                                      \
    }

    // ---- tap loop: CH = chunk, HI = 1 for X-hi phase (adds Wl product) ----
#define TAPS(CH, HI)                                                           \
    {                                                                          \
        const size_t tb0 = (((size_t)(b * 2 + (CH)) * 2 + 0) * 9) * 2048;      \
        const size_t tb1 = (((size_t)(b * 2 + (CH)) * 2 + 1) * 9) * 2048;      \
        const int sb = lq * 4 * 128 + ln * 8;                                  \
        _Pragma("unroll")                                                      \
        for (int tap = 0; tap < 9; ++tap) {                                    \
            s16x8 Ah[4], Al[4];                                                \
            _Pragma("unroll")                                                  \
            for (int oct = 0; oct < 4; ++oct) {                                \
                Ah[oct] = *(const s16x8*)(W + tb0 + (size_t)tap * 2048 + sb + oct * 128); \
                if (HI) Al[oct] = *(const s16x8*)(W + tb1 + (size_t)tap * 2048 + sb + oct * 128); \
            }                                                                  \
            const int ky = tap / 3;                                            \
            const int kx = tap - ky * 3;                                       \
            s16x8 Bv[2];                                                       \
            _Pragma("unroll")                                                  \
            for (int nt = 0; nt < 2; ++nt) {                                   \
                int col = qx * 32 + nt * 16 + ln + kx;                         \
                int pr  = col >> 1, u = col & 1;                               \
                Bv[nt] = *(const s16x8*)&lds_x[(ky * 520 + pr * 8 +            \
                          (((u << 2) | lq) ^ (pr & 7))) * 8];                  \
            }                                                                  \
            _Pragma("unroll")                                                  \
            for (int oct = 0; oct < 4; ++oct)                                  \
                _Pragma("unroll")                                              \
                for (int nt = 0; nt < 2; ++nt)                                 \
                    acc[oct][nt] = __builtin_amdgcn_mfma_f32_16x16x32_bf16(    \
                        Ah[oct], Bv[nt], acc[oct][nt], 0, 0, 0);               \
            if (HI) {                                                          \
                _Pragma("unroll")                                              \
                for (int oct = 0; oct < 4; ++oct)                              \
                    _Pragma("unroll")                                          \
                    for (int nt = 0; nt < 2; ++nt)                             \
                        acc[oct][nt] = __builtin_amdgcn_mfma_f32_16x16x32_bf16(\
                            Al[oct], Bv[nt], acc[oct][nt], 0, 0, 0);           \
            }                                                                  \
        }                                                                      \
    }

    // ---- schedule: planes (h,c0)=0, (l,c0)=2, (h,c1)=1, (l,c1)=3 ----
    ISSUE(0);
    WRITE_STG();           // vmcnt drain once (prologue)
    ISSUE(2);              // flies under TAPS of plane 0
    __syncthreads();

    TAPS(0, 1);            // Wh*Xh + Wl*Xh, chunk 0
    __syncthreads();
    WRITE_STG();
    ISSUE(1);
    __syncthreads();

    TAPS(0, 0);            // Wh*Xl, chunk 0
    __syncthreads();
    WRITE_STG();
    ISSUE(3);
    __syncthreads();

    TAPS(1, 1);            // chunk 1 hi
    __syncthreads();
    WRITE_STG();
    __syncthreads();

    TAPS(1, 0);            // chunk 1 lo

    // ---- epilogue: bias + store ----
    float bia[4][4];
#pragma unroll
    for (int oct = 0; oct < 4; ++oct)
#pragma unroll
        for (int r = 0; r < 4; ++r)
            bia[oct][r] = bias[b * OC_ + oct * 16 + lq * 4 + r];

    if (!final_layer) {
#pragma unroll
        for (int oct = 0; oct < 4; ++oct)
#pragma unroll
            for (int nt = 0; nt < 2; ++nt) {
                int px = qx * 32 + nt * 16 + ln;
                size_t pxl = (size_t)b * HW_ + py * W_ + px;
                int oc0   = oct * 16 + lq * 4;
                int chunk = oc0 >> 5;
                int off   = oc0 & 31;
                s16x4 hv, lv;
#pragma unroll
                for (int r = 0; r < 4; ++r) {
                    float v = acc[oct][nt][r] + bia[oct][r];
                    unsigned short h = f2bf(v);
                    hv[r] = (short)h;
                    lv[r] = (short)f2bf(v - bf2f(h));
                }
                *(s16x4*)(Ys + (size_t)(0 + chunk) * PSTR + pxl * 32 + off) = hv;
                *(s16x4*)(Ys + (size_t)(2 + chunk) * PSTR + pxl * 32 + off) = lv;
            }
    } else {
#pragma unroll
        for (int oct = 0; oct < 4; ++oct)
#pragma unroll
            for (int nt = 0; nt < 2; ++nt) {
                int px = qx * 32 + nt * 16 + ln;
#pragma unroll
                for (int r = 0; r < 4; ++r) {
                    int oc = oct * 16 + lq * 4 + r;
                    Yf[((size_t)(b * OC_ + oc)) * HW_ + py * W_ + px] =
                        acc[oct][nt][r] + bia[oct][r];
                }
            }
    }
#undef ISSUE
#undef WRITE_STG
#undef TAPS
}

// ---------------------------------------------------------------------------
// Launch
// ---------------------------------------------------------------------------
extern "C" void kernel_launch(void* const* d_in, const int* in_sizes, int n_in,
                              void* d_out, int out_size, void* d_ws, size_t ws_size,
                              hipStream_t stream) {
    const float* x   = (const float*)d_in[0];
    const float* cw1 = (const float*)d_in[1];
    const float* cw2 = (const float*)d_in[2];
    const float* w1  = (const float*)d_in[3];
    const float* w2  = (const float*)d_in[4];
    const float* w3  = (const float*)d_in[5];
    const float* b1  = (const float*)d_in[6];
    const float* b2  = (const float*)d_in[7];
    const float* b3  = (const float*)d_in[8];

    char* ws = (char*)d_ws;
    float* pooled = (float*)(ws + 0);            //  4 KB
    float* coeff  = (float*)(ws + 4096);         // 16 KB
    float* ab_all = (float*)(ws + 20480);        // 12 KB
    const size_t WSZ = (size_t)WELEM * 2;        // 2,359,296 B per layer (hi+lo)
    unsigned short* W1 = (unsigned short*)(ws + 32768);
    unsigned short* W2 = (unsigned short*)(ws + 32768 + 1 * WSZ);
    unsigned short* W3 = (unsigned short*)(ws + 32768 + 2 * WSZ);
    const size_t SOFF = 32768 + 3 * WSZ;                 // 7,110,656
    const size_t SSZ  = 4 * PSTR * 2;                    // 67,108,864 B per stage
    unsigned short* S0 = (unsigned short*)(ws + SOFF);
    unsigned short* S1 = (unsigned short*)(ws + SOFF + SSZ);
    // total = 141,328,384 B (unchanged)

    float* ab1 = ab_all;
    float* ab2 = ab_all + B_ * OC_;
    float* ab3 = ab_all + 2 * B_ * OC_;

    pool_kernel<<<B_ * C_, 256, 0, stream>>>(x, pooled);
    control_kernel<<<B_, 64, 0, stream>>>(pooled, cw1, cw2, b1, b2, b3, coeff, ab_all);
    {
        dim3 g(2304, 3);
        aggw_split<<<g, 256, 0, stream>>>(coeff, w1, w2, w3, W1, W2, W3);
    }
    {
        dim3 g(HW_ / 64, B_);
        xcvt_kernel<<<g, 256, 0, stream>>>(x, S0);
    }
    conv_mfma<<<2048, 256, 0, stream>>>(S0, W1, ab1, S1, nullptr, 0);
    conv_mfma<<<2048, 256, 0, stream>>>(S1, W2, ab2, S0, nullptr, 0);
    conv_mfma<<<2048, 256, 0, stream>>>(S0, W3, ab3, nullptr, (float*)d_out, 1);
}